// Round 14
// baseline (577.952 us; speedup 1.0000x reference)
//
#include <hip/hip_runtime.h>
#include <math.h>

// Problem constants
#define NTOK 16384
#define DDIM 4096
#define NEXP 64
#define KTOP 4

// GEMM config (V0 = R12 verified kernel)
#define SPLITK 4
#define KPER (DDIM / SPLITK)   // 1024
#define BK 32
#define NSTG (KPER / BK)       // 32
#define TPB 128
#define NBLK ((NTOK / TPB) * SPLITK)  // 512

typedef __attribute__((ext_vector_type(8))) short short8;
typedef __attribute__((ext_vector_type(4))) float f32x4;

__device__ __forceinline__ unsigned short f2bf_rtn(float x) {
    unsigned int b = __float_as_uint(x);
    return (unsigned short)((b + 0x7FFFu + ((b >> 16) & 1u)) >> 16);
}
__device__ __forceinline__ float bf2f(unsigned short h) {
    return __uint_as_float(((unsigned int)h) << 16);
}
__device__ __forceinline__ short8 mk8(unsigned int a, unsigned int b,
                                      unsigned int c, unsigned int d) {
    union { unsigned int u[4]; short8 s; } p;
    p.u[0] = a; p.u[1] = b; p.u[2] = c; p.u[3] = d;
    return p.s;
}
__device__ __forceinline__ void gl2lds16(const void* g, void* l) {
    __builtin_amdgcn_global_load_lds(
        (const __attribute__((address_space(1))) unsigned int*)g,
        (__attribute__((address_space(3))) unsigned int*)l, 16, 0, 0);
}

// ---------------- Kernel 1: split W into bf16 hi/lo, zero counts -------------
__global__ __launch_bounds__(256) void prep_kernel(
    const float* __restrict__ W, unsigned short* __restrict__ Whi,
    unsigned short* __restrict__ Wlo, float* __restrict__ counts)
{
    int idx = blockIdx.x * 256 + threadIdx.x;
    float x = W[idx];
    unsigned short h = f2bf_rtn(x);
    float lo = x - bf2f(h);
    Whi[idx] = h;
    Wlo[idx] = f2bf_rtn(lo);
    if (blockIdx.x == 0 && threadIdx.x < NEXP) counts[threadIdx.x] = 0.0f;
}

// ======== PROBE V1: staging-only, SCATTERED sources (R12 pattern), x3 ========
// Replicates R12's exact source addressing (8 x 128-B segments / instr at
// 16-KB row stride) with no consumers, no waits until the end. Measures the
// max delivery rate of the scattered gload_lds pattern.
__global__ __launch_bounds__(512, 4) void probe_scatter_kernel(
    const float* __restrict__ X, const unsigned short* __restrict__ Whi,
    const unsigned short* __restrict__ Wlo, float* __restrict__ scratch)
{
    __shared__ float          sX[512 * 2];        // shared dump area (races OK)
    __shared__ unsigned short sW[4096];

    const int tid  = threadIdx.x;
    const int lane = tid & 63;
    const int w    = tid >> 6;
    const int tb   = blockIdx.x >> 2;
    const int s    = blockIdx.x & 3;
    const int kbase = s * KPER;
    const int tok0 = tb * TPB;

    const int r0 = (w * 2    ) * 8 + (lane >> 3);
    const int r1 = (w * 2 + 1) * 8 + (lane >> 3);
    const int xp = lane & 7;
    const float* xsrc0 = X + (size_t)(tok0 + r0) * DDIM + kbase + ((xp ^ (r0 & 7)) << 2);
    const float* xsrc1 = X + (size_t)(tok0 + r1) * DDIM + kbase + ((xp ^ (r1 & 7)) << 2);
    const unsigned short* wsrc = ((w < 4) ? Whi : Wlo)
        + (size_t)((w & 3) * 16 + (lane & 15)) * DDIM + kbase + (lane >> 4) * 8;

    for (int rep = 0; rep < 3; ++rep) {
        for (int st = 0; st < NSTG; ++st) {
            gl2lds16(xsrc0 + st * BK, &sX[(w & 1) * 512]);
            gl2lds16(xsrc1 + st * BK, &sX[(w & 1) * 512 + 256]);
            gl2lds16(wsrc  + st * BK, &sW[(w & 3) * 512]);
        }
    }
    asm volatile("s_waitcnt vmcnt(0)" ::: "memory");
    __syncthreads();
    float v = sX[lane];                    // keep staging observable
    asm volatile("" :: "v"(v));
    if (v == 1234.56789f) scratch[tid] = v;
}

// ======== PROBE V2: staging-only, CONTIGUOUS 1-KB runs, same bytes, x3 =======
// Each instruction: 64 lanes x 16 B fully contiguous (one 1-KB run). Block
// sweeps a contiguous 512-KB X span. Same total bytes as V1's X+W.
__global__ __launch_bounds__(512, 4) void probe_contig_kernel(
    const float* __restrict__ X, float* __restrict__ scratch)
{
    __shared__ float sP[8 * 256];

    const int tid  = threadIdx.x;
    const int lane = tid & 63;
    const int w    = tid >> 6;
    // block covers floats [blockIdx*131072, +131072) = 512 KB
    const float* base = X + (size_t)blockIdx.x * 131072 + w * 16384 + lane * 4;

    for (int rep = 0; rep < 3; ++rep) {
        #pragma unroll 4
        for (int i = 0; i < 64; ++i)
            gl2lds16(base + i * 256, &sP[w * 256]);
        // match V1's byte count (V1 reads 96 KB/wave/rep vs 64 KB here): +32 KB
        #pragma unroll 4
        for (int i = 0; i < 32; ++i)
            gl2lds16(base + i * 256 + 128, &sP[w * 256]);
    }
    asm volatile("s_waitcnt vmcnt(0)" ::: "memory");
    __syncthreads();
    float v = sP[lane];
    asm volatile("" :: "v"(v));
    if (v == 1234.56789f) scratch[tid] = v;
}

// ======== PROBE V3: compute-only (stage once, 32 stages x6 on stale LDS) =====
__global__ __launch_bounds__(512, 4) void probe_compute_kernel(
    const float* __restrict__ X, const unsigned short* __restrict__ Whi,
    const unsigned short* __restrict__ Wlo, float* __restrict__ part)
{
    __shared__ float          sX[TPB * BK];
    __shared__ unsigned short sH[NEXP * BK];
    __shared__ unsigned short sL[NEXP * BK];

    const int tid  = threadIdx.x;
    const int lane = tid & 63;
    const int w    = tid >> 6;
    const int tb   = blockIdx.x >> 2;
    const int s    = blockIdx.x & 3;
    const int kbase = s * KPER;
    const int tok0 = tb * TPB;

    const int r0 = (w * 2    ) * 8 + (lane >> 3);
    const int r1 = (w * 2 + 1) * 8 + (lane >> 3);
    const int xp = lane & 7;
    const float* xsrc0 = X + (size_t)(tok0 + r0) * DDIM + kbase + ((xp ^ (r0 & 7)) << 2);
    const float* xsrc1 = X + (size_t)(tok0 + r1) * DDIM + kbase + ((xp ^ (r1 & 7)) << 2);
    const unsigned short* wsrc = ((w < 4) ? Whi : Wlo)
        + (size_t)((w & 3) * 16 + (lane & 15)) * DDIM + kbase + (lane >> 4) * 8;
    unsigned short* wdstp = ((w < 4) ? sH : sL) + (w & 3) * 512 + lane * 8;

    gl2lds16(xsrc0, &sX[(w * 2) * 256]);
    gl2lds16(xsrc1, &sX[(w * 2 + 1) * 256]);
    gl2lds16(wsrc, wdstp);
    __syncthreads();

    const int fr = lane & 15;
    const int fg = lane >> 4;
    const int aoff = (w * 16 + fr) * BK;
    const int akey = fr & 7;

    f32x4 acc[4];
    #pragma unroll
    for (int ng = 0; ng < 4; ++ng) acc[ng] = (f32x4){0.f, 0.f, 0.f, 0.f};

    for (int rep = 0; rep < 6; ++rep) {
        #pragma unroll
        for (int st = 0; st < NSTG; ++st) {
            const float4 qa = *(const float4*)&sX[aoff + (((fg * 2    ) ^ akey) << 2)];
            const float4 qb = *(const float4*)&sX[aoff + (((fg * 2 + 1) ^ akey) << 2)];
            const unsigned int u0 = __float_as_uint(qa.x), u1 = __float_as_uint(qa.y);
            const unsigned int u2 = __float_as_uint(qa.z), u3 = __float_as_uint(qa.w);
            const unsigned int u4 = __float_as_uint(qb.x), u5 = __float_as_uint(qb.y);
            const unsigned int u6 = __float_as_uint(qb.z), u7 = __float_as_uint(qb.w);
            const short8 ahi = mk8((u0 >> 16) | (u1 & 0xFFFF0000u),
                                   (u2 >> 16) | (u3 & 0xFFFF0000u),
                                   (u4 >> 16) | (u5 & 0xFFFF0000u),
                                   (u6 >> 16) | (u7 & 0xFFFF0000u));
            const float l0 = qa.x - __uint_as_float(u0 & 0xFFFF0000u);
            const float l1 = qa.y - __uint_as_float(u1 & 0xFFFF0000u);
            const float l2 = qa.z - __uint_as_float(u2 & 0xFFFF0000u);
            const float l3 = qa.w - __uint_as_float(u3 & 0xFFFF0000u);
            const float l4 = qb.x - __uint_as_float(u4 & 0xFFFF0000u);
            const float l5 = qb.y - __uint_as_float(u5 & 0xFFFF0000u);
            const float l6 = qb.z - __uint_as_float(u6 & 0xFFFF0000u);
            const float l7 = qb.w - __uint_as_float(u7 & 0xFFFF0000u);
            const short8 alo = mk8(
                (__float_as_uint(l0) >> 16) | (__float_as_uint(l1) & 0xFFFF0000u),
                (__float_as_uint(l2) >> 16) | (__float_as_uint(l3) & 0xFFFF0000u),
                (__float_as_uint(l4) >> 16) | (__float_as_uint(l5) & 0xFFFF0000u),
                (__float_as_uint(l6) >> 16) | (__float_as_uint(l7) & 0xFFFF0000u));
            #pragma unroll
            for (int ng = 0; ng < 4; ++ng) {
                const int bo = ng * 512 + fg * 128 + fr * 8;
                const short8 bh = *(const short8*)&sH[bo];
                const short8 bl = *(const short8*)&sL[bo];
                acc[ng] = __builtin_amdgcn_mfma_f32_16x16x32_bf16(ahi, bh, acc[ng], 0, 0, 0);
                acc[ng] = __builtin_amdgcn_mfma_f32_16x16x32_bf16(ahi, bl, acc[ng], 0, 0, 0);
                acc[ng] = __builtin_amdgcn_mfma_f32_16x16x32_bf16(alo, bh, acc[ng], 0, 0, 0);
            }
            __builtin_amdgcn_s_barrier();
        }
    }

    // garbage partials (overwritten by the full gemm which runs after)
    #pragma unroll
    for (int r = 0; r < 4; ++r) {
        const int n = tok0 + w * 16 + fg * 4 + r;
        float* __restrict__ pp = part + ((size_t)n * SPLITK + s) * NEXP;
        #pragma unroll
        for (int ng = 0; ng < 4; ++ng)
            pp[ng * 16 + fr] = acc[ng][r];
    }
}

// ======== V0: R12 verified full gemm (3-deep no-drain), writes correct part ==
__global__ __launch_bounds__(512, 4) void gemm_kernel(
    const float* __restrict__ X, const unsigned short* __restrict__ Whi,
    const unsigned short* __restrict__ Wlo, float* __restrict__ part)
{
    __shared__ float          sX[3][TPB * BK];
    __shared__ unsigned short sH[3][NEXP * BK];
    __shared__ unsigned short sL[3][NEXP * BK];

    const int tid  = threadIdx.x;
    const int lane = tid & 63;
    const int w    = tid >> 6;
    const int tb   = blockIdx.x >> 2;
    const int s    = blockIdx.x & 3;
    const int kbase = s * KPER;
    const int tok0 = tb * TPB;

    const int r0 = (w * 2    ) * 8 + (lane >> 3);
    const int r1 = (w * 2 + 1) * 8 + (lane >> 3);
    const int xp = lane & 7;
    const float* xsrc0 = X + (size_t)(tok0 + r0) * DDIM + kbase + ((xp ^ (r0 & 7)) << 2);
    const float* xsrc1 = X + (size_t)(tok0 + r1) * DDIM + kbase + ((xp ^ (r1 & 7)) << 2);
    const int xdst0 = (w * 2    ) * 256;
    const int xdst1 = (w * 2 + 1) * 256;

    const unsigned short* const wtab_src = (w < 4) ? Whi : Wlo;
    const int eb = w & 3;
    const int we = eb * 16 + (lane & 15);
    const unsigned short* wsrc = wtab_src + (size_t)we * DDIM + kbase + (lane >> 4) * 8;
    const int wdst = eb * 512 + lane * 8;
    unsigned short (* const wtab_dst)[NEXP * BK] = (w < 4) ? sH : sL;

#define ISSUE(st_, slot_)                                                   \
    {                                                                       \
        gl2lds16(xsrc0 + (st_) * BK, &sX[slot_][xdst0]);                    \
        gl2lds16(xsrc1 + (st_) * BK, &sX[slot_][xdst1]);                    \
        gl2lds16(wsrc  + (st_) * BK, &wtab_dst[slot_][wdst]);               \
    }

    ISSUE(0, 0)
    ISSUE(1, 1)
    __syncthreads();

    const int fr = lane & 15;
    const int fg = lane >> 4;
    const int aoff = (w * 16 + fr) * BK;
    const int akey = fr & 7;

    f32x4 acc[4];
    #pragma unroll
    for (int ng = 0; ng < 4; ++ng) acc[ng] = (f32x4){0.f, 0.f, 0.f, 0.f};

    #pragma unroll
    for (int st = 0; st < NSTG; ++st) {
        const int slot = st % 3;
        if (st + 2 < NSTG) ISSUE(st + 2, (st + 2) % 3)

        const float4 qa = *(const float4*)&sX[slot][aoff + (((fg * 2    ) ^ akey) << 2)];
        const float4 qb = *(const float4*)&sX[slot][aoff + (((fg * 2 + 1) ^ akey) << 2)];
        const unsigned int u0 = __float_as_uint(qa.x), u1 = __float_as_uint(qa.y);
        const unsigned int u2 = __float_as_uint(qa.z), u3 = __float_as_uint(qa.w);
        const unsigned int u4 = __float_as_uint(qb.x), u5 = __float_as_uint(qb.y);
        const unsigned int u6 = __float_as_uint(qb.z), u7 = __float_as_uint(qb.w);
        const short8 ahi = mk8((u0 >> 16) | (u1 & 0xFFFF0000u),
                               (u2 >> 16) | (u3 & 0xFFFF0000u),
                               (u4 >> 16) | (u5 & 0xFFFF0000u),
                               (u6 >> 16) | (u7 & 0xFFFF0000u));
        const float l0 = qa.x - __uint_as_float(u0 & 0xFFFF0000u);
        const float l1 = qa.y - __uint_as_float(u1 & 0xFFFF0000u);
        const float l2 = qa.z - __uint_as_float(u2 & 0xFFFF0000u);
        const float l3 = qa.w - __uint_as_float(u3 & 0xFFFF0000u);
        const float l4 = qb.x - __uint_as_float(u4 & 0xFFFF0000u);
        const float l5 = qb.y - __uint_as_float(u5 & 0xFFFF0000u);
        const float l6 = qb.z - __uint_as_float(u6 & 0xFFFF0000u);
        const float l7 = qb.w - __uint_as_float(u7 & 0xFFFF0000u);
        const short8 alo = mk8(
            (__float_as_uint(l0) >> 16) | (__float_as_uint(l1) & 0xFFFF0000u),
            (__float_as_uint(l2) >> 16) | (__float_as_uint(l3) & 0xFFFF0000u),
            (__float_as_uint(l4) >> 16) | (__float_as_uint(l5) & 0xFFFF0000u),
            (__float_as_uint(l6) >> 16) | (__float_as_uint(l7) & 0xFFFF0000u));

        #pragma unroll
        for (int ng = 0; ng < 4; ++ng) {
            const int bo = ng * 512 + fg * 128 + fr * 8;
            const short8 bh = *(const short8*)&sH[slot][bo];
            const short8 bl = *(const short8*)&sL[slot][bo];
            acc[ng] = __builtin_amdgcn_mfma_f32_16x16x32_bf16(ahi, bh, acc[ng], 0, 0, 0);
            acc[ng] = __builtin_amdgcn_mfma_f32_16x16x32_bf16(ahi, bl, acc[ng], 0, 0, 0);
            acc[ng] = __builtin_amdgcn_mfma_f32_16x16x32_bf16(alo, bh, acc[ng], 0, 0, 0);
        }

        if (st < NSTG - 1) {
            if (st < NSTG - 2) {
                asm volatile("s_waitcnt vmcnt(3)" ::: "memory");
            } else {
                asm volatile("s_waitcnt vmcnt(0)" ::: "memory");
            }
            __builtin_amdgcn_sched_barrier(0);
            __builtin_amdgcn_s_barrier();
        }
    }
#undef ISSUE

    #pragma unroll
    for (int r = 0; r < 4; ++r) {
        const int n = tok0 + w * 16 + fg * 4 + r;
        float* __restrict__ pp = part + ((size_t)n * SPLITK + s) * NEXP;
        #pragma unroll
        for (int ng = 0; ng < 4; ++ng)
            pp[ng * 16 + fr] = acc[ng][r];
    }
}

// ---------------- Kernel 3: softmax + group-limited top-k routing ------------
__global__ __launch_bounds__(256) void route_kernel(
    const float* __restrict__ part, float* __restrict__ outW,
    float* __restrict__ outI, float* __restrict__ counts)
{
    __shared__ int hist[NEXP];
    const int tid = threadIdx.x;
    if (tid < NEXP) hist[tid] = 0;
    __syncthreads();

    const int lane = tid & 63;
    const int wv   = tid >> 6;
    const int tok_base = blockIdx.x * 32 + wv * 8;

    for (int t = 0; t < 8; ++t) {
        const int n = tok_base + t;
        float L = 0.0f;
        #pragma unroll
        for (int s = 0; s < SPLITK; ++s)
            L += part[((size_t)n * SPLITK + s) * NEXP + lane];

        float m = L;
        #pragma unroll
        for (int off = 32; off > 0; off >>= 1) m = fmaxf(m, __shfl_xor(m, off));
        float p = expf(L - m);
        float ssum = p;
        #pragma unroll
        for (int off = 32; off > 0; off >>= 1) ssum += __shfl_xor(ssum, off);
        const float score = p / ssum;

        float gm = score;
        gm = fmaxf(gm, __shfl_xor(gm, 1));
        gm = fmaxf(gm, __shfl_xor(gm, 2));
        gm = fmaxf(gm, __shfl_xor(gm, 4));

        float ga[8];
        #pragma unroll
        for (int g = 0; g < 8; ++g) ga[g] = __shfl(gm, g * 8);
        unsigned selmask = 0u;
        #pragma unroll
        for (int r = 0; r < 4; ++r) {
            float best = -INFINITY; int bg = 0;
            #pragma unroll
            for (int g = 0; g < 8; ++g) {
                bool taken  = (selmask >> g) & 1u;
                bool better = (!taken) && (ga[g] > best);
                bg   = better ? g : bg;
                best = better ? ga[g] : best;
            }
            selmask |= (1u << bg);
        }

        float ms = ((selmask >> (lane >> 3)) & 1u) ? score : -INFINITY;
        float wk[4]; int wi[4];
        #pragma unroll
        for (int r = 0; r < 4; ++r) {
            float v = ms; int ix = lane;
            #pragma unroll
            for (int off = 32; off > 0; off >>= 1) {
                float vo = __shfl_xor(v, off);
                int   io = __shfl_xor(ix, off);
                if (vo > v || (vo == v && io < ix)) { v = vo; ix = io; }
            }
            wk[r] = v; wi[r] = ix;
            if (lane == ix) ms = -INFINITY;
        }

        if (lane == 0) {
            *(float4*)&outW[(size_t)n * 4] = make_float4(wk[0], wk[1], wk[2], wk[3]);
            *(float4*)&outI[(size_t)n * 4] =
                make_float4((float)wi[0], (float)wi[1], (float)wi[2], (float)wi[3]);
            atomicAdd(&hist[wi[0]], 1);
            atomicAdd(&hist[wi[1]], 1);
            atomicAdd(&hist[wi[2]], 1);
            atomicAdd(&hist[wi[3]], 1);
        }
    }

    __syncthreads();
    if (tid < NEXP) atomicAdd(&counts[tid], (float)hist[tid]);
}

extern "C" void kernel_launch(void* const* d_in, const int* in_sizes, int n_in,
                              void* d_out, int out_size, void* d_ws, size_t ws_size,
                              hipStream_t stream) {
    const float* X = (const float*)d_in[0];
    const float* W = (const float*)d_in[1];

    float* outW   = (float*)d_out;
    float* outI   = outW + (size_t)NTOK * KTOP;
    float* counts = outW + (size_t)2 * NTOK * KTOP;

    float*          part = (float*)d_ws;                              // 16 MB
    unsigned short* Whi  = (unsigned short*)(part + (size_t)NTOK * SPLITK * NEXP);
    unsigned short* Wlo  = Whi + (size_t)NEXP * DDIM;
    float*          scratch = (float*)(Wlo + (size_t)NEXP * DDIM);    // probe sink

    prep_kernel<<<(NEXP * DDIM) / 256, 256, 0, stream>>>(W, Whi, Wlo, counts);
    // --- probes (do not affect final output) ---
    probe_scatter_kernel<<<NBLK, 512, 0, stream>>>(X, Whi, Wlo, scratch);
    probe_contig_kernel<<<512, 512, 0, stream>>>(X, scratch);
    probe_compute_kernel<<<NBLK, 512, 0, stream>>>(X, Whi, Wlo, part);
    // --- real computation (overwrites probe garbage) ---
    gemm_kernel<<<NBLK, 512, 0, stream>>>(X, Whi, Wlo, part);
    route_kernel<<<NTOK / 32, 256, 0, stream>>>(part, outW, outI, counts);
}

// Round 15
// 119.777 us; speedup vs baseline: 4.8252x; 4.8252x over previous
//
#include <hip/hip_runtime.h>
#include <math.h>

// Problem constants
#define NTOK 16384
#define DDIM 4096
#define NEXP 64
#define KTOP 4

// GEMM config
#define SPLITK 16
#define KPER 256               // floats per split per row = 1 KB (one instr!)
#define TPB 64                 // tokens per block
#define NBLK ((NTOK / TPB) * SPLITK)   // 4096 blocks -> 16/CU, 2 resident
#define WP_HL 262144           // shorts: Wp hi/lo plane stride (16*32*64*8)

typedef __attribute__((ext_vector_type(8))) short short8;
typedef __attribute__((ext_vector_type(4))) float f32x4;

// ws layout: part [NTOK][SPLITK][NEXP] f32 = 64 MB ; Wp [2][16][32][64][8] ushort = 1 MB

__device__ __forceinline__ unsigned short f2bf_rtn(float x) {
    unsigned int b = __float_as_uint(x);
    return (unsigned short)((b + 0x7FFFu + ((b >> 16) & 1u)) >> 16);
}
__device__ __forceinline__ float bf2f(unsigned short h) {
    return __uint_as_float(((unsigned int)h) << 16);
}
__device__ __forceinline__ void gl2lds16(const void* g, void* l) {
    __builtin_amdgcn_global_load_lds(
        (const __attribute__((address_space(1))) unsigned int*)g,
        (__attribute__((address_space(3))) unsigned int*)l, 16, 0, 0);
}
// pack hi16(x0),hi16(x1) -> one u32 (x0 in low half): v_perm_b32
__device__ __forceinline__ unsigned int pack_hi(unsigned int u0, unsigned int u1) {
    return __builtin_amdgcn_perm(u1, u0, 0x07060302u);
}

// ---------------- Kernel 1: W -> piece-major bf16 hi/lo, zero counts ---------
// Wp[hl][s][p][e][i]: fragment for (split s, k-piece p, expert e) is 16 B at
// ((s*32+p)*64+e)*8 -- a wave's 64 lanes (16 experts x 4 pieces) read 4x256-B
// contiguous runs. First-touch HBM efficient; L2-resident afterwards.
__global__ __launch_bounds__(256) void prep_kernel(
    const float* __restrict__ W, unsigned short* __restrict__ Wp,
    float* __restrict__ counts)
{
    int idx = blockIdx.x * 256 + threadIdx.x;   // e*4096 + d
    int e = idx >> 12, d = idx & 4095;
    float x = W[idx];
    unsigned short h = f2bf_rtn(x);
    float lo = x - bf2f(h);
    int s = d >> 8, p = (d >> 3) & 31, i = d & 7;
    size_t o = (((size_t)s * 32 + p) * 64 + e) * 8 + i;
    Wp[o]         = h;
    Wp[WP_HL + o] = f2bf_rtn(lo);
    if (blockIdx.x == 0 && threadIdx.x < NEXP) counts[threadIdx.x] = 0.0f;
}

// ---------------- Kernel 2: bf16x3 MFMA GEMM, 1-KB-run staging ---------------
// 4096 blocks x 512 threads (8 waves: 2qm x 4qn), LDS 64 KB -> 2 blocks/CU
// (co-resident block covers the fill). Each X staging instruction delivers ONE
// ROW'S ENTIRE 1-KB k-slice contiguously (the R13 probe's fast pattern).
// W: 16 register b128 loads from piece-major Wp (no LDS, no manual waits).
// One __syncthreads total; 8 barrier-free k-steps.
__global__ __launch_bounds__(512, 4) void gemm_kernel(
    const float* __restrict__ X, const unsigned short* __restrict__ Wp,
    float* __restrict__ part)
{
    __shared__ float sX[TPB * KPER];   // 64 KB

    const int tid  = threadIdx.x;
    const int lane = tid & 63;
    const int w    = tid >> 6;                 // wave 0..7
    const int qm   = w >> 2;                   // token half   0..1 (32 rows)
    const int qn   = w & 3;                    // expert quarter 0..3 (16 exp)
    const int tb   = blockIdx.x >> 4;          // token block 0..255
    const int s    = blockIdx.x & 15;          // k-split     0..15
    const int kbase = s * KPER;
    const int tok0 = tb * TPB;

    // ---- X staging: 8 instrs/wave, each = one row x 1 KB CONTIGUOUS --------
    // LDS[r][p] holds X[r][p ^ (r&7)] (16-B pieces; involution source-side).
    #pragma unroll
    for (int i = 0; i < 8; ++i) {
        const int r = w * 8 + i;
        const float* src = X + (size_t)(tok0 + r) * DDIM + kbase
                         + ((lane ^ (r & 7)) << 2);
        gl2lds16(src, &sX[r * KPER]);
    }

    // ---- W fragments -> registers (compiler-managed waits, L2-resident) ----
    const int fr = lane & 15;                  // token row / expert col in frag
    const int fg = lane >> 4;                  // k subgroup 0..3
    const size_t e8 = (size_t)(qn * 16 + fr) * 8;
    short8 bh[8], bl[8];
    #pragma unroll
    for (int ks = 0; ks < 8; ++ks) {
        const size_t o = ((size_t)(s * 32 + ks * 4 + fg)) * 512 + e8;
        bh[ks] = *(const short8*)(Wp + o);
        bl[ks] = *(const short8*)(Wp + WP_HL + o);
    }

    __syncthreads();   // the one barrier: X fully staged (drain covered by co-block)

    // ---- A-read bases (XOR swizzle folds to compile-time imm per ks) -------
    const int key = fr & 7;
    int baseA[2][2];
    #pragma unroll
    for (int mg = 0; mg < 2; ++mg) {
        const int row = qm * 32 + mg * 16 + fr;
        baseA[mg][0] = row * KPER + (((fg * 2    ) ^ key) << 2);
        baseA[mg][1] = row * KPER + (((fg * 2 + 1) ^ key) << 2);
    }

    f32x4 acc[2];
    acc[0] = (f32x4){0.f, 0.f, 0.f, 0.f};
    acc[1] = (f32x4){0.f, 0.f, 0.f, 0.f};

    #pragma unroll
    for (int ks = 0; ks < 8; ++ks) {
        #pragma unroll
        for (int mg = 0; mg < 2; ++mg) {
            const float4 qa = *(const float4*)&sX[baseA[mg][0] + ks * 32];
            const float4 qb = *(const float4*)&sX[baseA[mg][1] + ks * 32];

            // RTZ split fp32 -> bf16 hi/lo (v_perm packing)
            const unsigned int u0 = __float_as_uint(qa.x), u1 = __float_as_uint(qa.y);
            const unsigned int u2 = __float_as_uint(qa.z), u3 = __float_as_uint(qa.w);
            const unsigned int u4 = __float_as_uint(qb.x), u5 = __float_as_uint(qb.y);
            const unsigned int u6 = __float_as_uint(qb.z), u7 = __float_as_uint(qb.w);
            union { unsigned int u[4]; short8 s8; } ah, al;
            ah.u[0] = pack_hi(u0, u1);
            ah.u[1] = pack_hi(u2, u3);
            ah.u[2] = pack_hi(u4, u5);
            ah.u[3] = pack_hi(u6, u7);
            const float l0 = qa.x - __uint_as_float(u0 & 0xFFFF0000u);
            const float l1 = qa.y - __uint_as_float(u1 & 0xFFFF0000u);
            const float l2 = qa.z - __uint_as_float(u2 & 0xFFFF0000u);
            const float l3 = qa.w - __uint_as_float(u3 & 0xFFFF0000u);
            const float l4 = qb.x - __uint_as_float(u4 & 0xFFFF0000u);
            const float l5 = qb.y - __uint_as_float(u5 & 0xFFFF0000u);
            const float l6 = qb.z - __uint_as_float(u6 & 0xFFFF0000u);
            const float l7 = qb.w - __uint_as_float(u7 & 0xFFFF0000u);
            al.u[0] = pack_hi(__float_as_uint(l0), __float_as_uint(l1));
            al.u[1] = pack_hi(__float_as_uint(l2), __float_as_uint(l3));
            al.u[2] = pack_hi(__float_as_uint(l4), __float_as_uint(l5));
            al.u[3] = pack_hi(__float_as_uint(l6), __float_as_uint(l7));

            acc[mg] = __builtin_amdgcn_mfma_f32_16x16x32_bf16(ah.s8, bh[ks], acc[mg], 0, 0, 0);
            acc[mg] = __builtin_amdgcn_mfma_f32_16x16x32_bf16(ah.s8, bl[ks], acc[mg], 0, 0, 0);
            acc[mg] = __builtin_amdgcn_mfma_f32_16x16x32_bf16(al.s8, bh[ks], acc[mg], 0, 0, 0);
        }
    }

    // ---- store partials [n][s][e] ----
    // C/D layout: col = fr (expert), row = fg*4 + r (token)
    #pragma unroll
    for (int mg = 0; mg < 2; ++mg)
        #pragma unroll
        for (int r = 0; r < 4; ++r) {
            const int n = tok0 + qm * 32 + mg * 16 + fg * 4 + r;
            part[((size_t)n * SPLITK + s) * NEXP + qn * 16 + fr] = acc[mg][r];
        }
}

// ---------------- Kernel 3: softmax + group-limited top-k routing ------------
__global__ __launch_bounds__(256) void route_kernel(
    const float* __restrict__ part, float* __restrict__ outW,
    float* __restrict__ outI, float* __restrict__ counts)
{
    __shared__ int hist[NEXP];
    const int tid = threadIdx.x;
    if (tid < NEXP) hist[tid] = 0;
    __syncthreads();

    const int lane = tid & 63;
    const int wv   = tid >> 6;   // wave 0..3
    const int tok_base = blockIdx.x * 32 + wv * 8;

    for (int t = 0; t < 8; ++t) {
        const int n = tok_base + t;
        // sum split-K partials (layout [n][s][e]): 4 KB contiguous per token
        float L = 0.0f;
        #pragma unroll
        for (int s = 0; s < SPLITK; ++s)
            L += part[((size_t)n * SPLITK + s) * NEXP + lane];

        // softmax over 64 experts (wave = expert axis)
        float m = L;
        #pragma unroll
        for (int off = 32; off > 0; off >>= 1) m = fmaxf(m, __shfl_xor(m, off));
        float p = expf(L - m);
        float ssum = p;
        #pragma unroll
        for (int off = 32; off > 0; off >>= 1) ssum += __shfl_xor(ssum, off);
        const float score = p / ssum;

        // group max within each 8-lane group
        float gm = score;
        gm = fmaxf(gm, __shfl_xor(gm, 1));
        gm = fmaxf(gm, __shfl_xor(gm, 2));
        gm = fmaxf(gm, __shfl_xor(gm, 4));

        // top-4 groups (ties -> lower index)
        float ga[8];
        #pragma unroll
        for (int g = 0; g < 8; ++g) ga[g] = __shfl(gm, g * 8);
        unsigned selmask = 0u;
        #pragma unroll
        for (int r = 0; r < 4; ++r) {
            float best = -INFINITY; int bg = 0;
            #pragma unroll
            for (int g = 0; g < 8; ++g) {
                bool taken  = (selmask >> g) & 1u;
                bool better = (!taken) && (ga[g] > best);
                bg   = better ? g : bg;
                best = better ? ga[g] : best;
            }
            selmask |= (1u << bg);
        }

        // mask non-selected groups, wave-wide top-4 (ties -> lower idx)
        float ms = ((selmask >> (lane >> 3)) & 1u) ? score : -INFINITY;
        float wk[4]; int wi[4];
        #pragma unroll
        for (int r = 0; r < 4; ++r) {
            float v = ms; int ix = lane;
            #pragma unroll
            for (int off = 32; off > 0; off >>= 1) {
                float vo = __shfl_xor(v, off);
                int   io = __shfl_xor(ix, off);
                if (vo > v || (vo == v && io < ix)) { v = vo; ix = io; }
            }
            wk[r] = v; wi[r] = ix;
            if (lane == ix) ms = -INFINITY;
        }

        if (lane == 0) {
            *(float4*)&outW[(size_t)n * 4] = make_float4(wk[0], wk[1], wk[2], wk[3]);
            *(float4*)&outI[(size_t)n * 4] =
                make_float4((float)wi[0], (float)wi[1], (float)wi[2], (float)wi[3]);
            atomicAdd(&hist[wi[0]], 1);
            atomicAdd(&hist[wi[1]], 1);
            atomicAdd(&hist[wi[2]], 1);
            atomicAdd(&hist[wi[3]], 1);
        }
    }

    __syncthreads();
    if (tid < NEXP) atomicAdd(&counts[tid], (float)hist[tid]);
}

extern "C" void kernel_launch(void* const* d_in, const int* in_sizes, int n_in,
                              void* d_out, int out_size, void* d_ws, size_t ws_size,
                              hipStream_t stream) {
    const float* X = (const float*)d_in[0];
    const float* W = (const float*)d_in[1];

    float* outW   = (float*)d_out;                    // [N,4] weights
    float* outI   = outW + (size_t)NTOK * KTOP;       // [N,4] indices (as float)
    float* counts = outW + (size_t)2 * NTOK * KTOP;   // [64]  counts  (as float)

    float*          part = (float*)d_ws;                              // 64 MB
    unsigned short* Wp   = (unsigned short*)(part + (size_t)NTOK * SPLITK * NEXP);

    prep_kernel<<<(NEXP * DDIM) / 256, 256, 0, stream>>>(W, Wp, counts);
    gemm_kernel<<<NBLK, 512, 0, stream>>>(X, Wp, part);
    route_kernel<<<NTOK / 32, 256, 0, stream>>>(part, outW, outI, counts);
}

// Round 16
// 115.092 us; speedup vs baseline: 5.0217x; 1.0407x over previous
//
#include <hip/hip_runtime.h>
#include <math.h>

// Problem constants
#define NTOK 16384
#define DDIM 4096
#define NEXP 64
#define KTOP 4

// GEMM config
#define SPLITK 4
#define KPER (DDIM / SPLITK)   // 1024 k per split
#define BK 128                 // floats per stage (512 B/row)
#define NSTG (KPER / BK)       // 8 stages
#define TPB 64                 // tokens per block
#define NBLK ((NTOK / TPB) * SPLITK)  // 1024 blocks -> 2/CU resident
#define WP_HL 262144           // shorts: Wp hi/lo plane stride (512*64*8)

typedef __attribute__((ext_vector_type(8))) short short8;
typedef __attribute__((ext_vector_type(4))) float f32x4;

// ws layout: part [NTOK][SPLITK][NEXP] f32 = 16 MB ; Wp [2][512][64][8] ushort = 1 MB

__device__ __forceinline__ unsigned short f2bf_rtn(float x) {
    unsigned int b = __float_as_uint(x);
    return (unsigned short)((b + 0x7FFFu + ((b >> 16) & 1u)) >> 16);
}
__device__ __forceinline__ float bf2f(unsigned short h) {
    return __uint_as_float(((unsigned int)h) << 16);
}
__device__ __forceinline__ void gl2lds16(const void* g, void* l) {
    __builtin_amdgcn_global_load_lds(
        (const __attribute__((address_space(1))) unsigned int*)g,
        (__attribute__((address_space(3))) unsigned int*)l, 16, 0, 0);
}
// pack hi16(x0),hi16(x1) -> one u32: v_perm_b32
__device__ __forceinline__ unsigned int pack_hi(unsigned int u0, unsigned int u1) {
    return __builtin_amdgcn_perm(u1, u0, 0x07060302u);
}

// ---------------- Kernel 1: W -> piece-major bf16 hi/lo, zero counts ---------
// Wp[hl][c32][e][8]: fragment (global 8-float piece c32, expert e) is 16 B at
// (c32*64+e)*8. A wave's frag loads = 4 contiguous 256-B runs. L2-resident.
__global__ __launch_bounds__(256) void prep_kernel(
    const float* __restrict__ W, unsigned short* __restrict__ Wp,
    float* __restrict__ counts)
{
    int idx = blockIdx.x * 256 + threadIdx.x;   // e*4096 + d
    int e = idx >> 12, d = idx & 4095;
    float x = W[idx];
    unsigned short h = f2bf_rtn(x);
    float lo = x - bf2f(h);
    size_t o = (((size_t)(d >> 3)) * 64 + e) * 8 + (d & 7);
    Wp[o]         = h;
    Wp[WP_HL + o] = f2bf_rtn(lo);
    if (blockIdx.x == 0 && threadIdx.x < NEXP) counts[threadIdx.x] = 0.0f;
}

// ---------------- Kernel 2: bf16x3 MFMA GEMM, contiguous-staged pipeline -----
// 1024 blocks x 512 threads (8 waves: 2qm x 4qn), LDS 64 KB -> 2 blocks/CU.
// R8's pipelined skeleton + R13's fast staging pattern: each X staging instr
// delivers 1 KB CONTIGUOUS (2 rows x 512 B). W: 8 b128 register loads/stage
// from piece-major Wp (L2, issued before the X DMAs -> FIFO keeps X in
// flight). Per-stage __syncthreads; co-resident block covers the drain.
__global__ __launch_bounds__(512, 4) void gemm_kernel(
    const float* __restrict__ X, const unsigned short* __restrict__ Wp,
    float* __restrict__ part)
{
    __shared__ float sX[2][TPB * BK];   // 2 x 32 KB

    const int tid  = threadIdx.x;
    const int lane = tid & 63;
    const int w    = tid >> 6;                 // wave 0..7
    const int qm   = w >> 2;                   // token half   0..1
    const int qn   = w & 3;                    // expert quarter 0..3
    const int tb   = blockIdx.x >> 2;          // token block 0..255
    const int s    = blockIdx.x & 3;           // k-split     0..3
    const int kbase = s * KPER;
    const int tok0 = tb * TPB;

    // ---- X staging: 4 instr/wave/stage; instr i covers rows {w*8+i*2, +1} --
    // lane -> row r = w*8+i*2+(lane>>5), 16-B piece p = lane&31.
    // LDS[r][p] holds X[r][p ^ (r&7)] (involution, source-side; dest linear).
    const float* xsrc[4];
    int xdst[4];
    #pragma unroll
    for (int i = 0; i < 4; ++i) {
        const int r = w * 8 + i * 2 + (lane >> 5);
        const int p = lane & 31;
        xsrc[i] = X + (size_t)(tok0 + r) * DDIM + kbase + ((p ^ (r & 7)) << 2);
        xdst[i] = (w * 8 + i * 2) * BK;        // wave-uniform float offset
    }

#define XISSUE(st_, buf_)                                                   \
    {                                                                       \
        _Pragma("unroll")                                                   \
        for (int i = 0; i < 4; ++i)                                         \
            gl2lds16(xsrc[i] + (st_) * BK, &sX[buf_][xdst[i]]);             \
    }

    // ---- prologue: stage 0 ----
    XISSUE(0, 0)
    __syncthreads();

    // ---- fragment geometry ----
    const int fr  = lane & 15;                 // token row / expert col
    const int fg  = lane >> 4;                 // k subgroup 0..3
    const int key = fr & 7;
    const int e8    = (qn * 16 + fr) * 8;      // Wp expert offset (shorts)
    const int pbase = kbase >> 3;              // global 8-float piece base
    int rowA[2];
    rowA[0] = (qm * 32 + fr) * BK;
    rowA[1] = (qm * 32 + 16 + fr) * BK;

    f32x4 acc[2];
    acc[0] = (f32x4){0.f, 0.f, 0.f, 0.f};
    acc[1] = (f32x4){0.f, 0.f, 0.f, 0.f};

    #pragma unroll
    for (int t = 0; t < NSTG; ++t) {
        // ---- W regs for this stage: 8 b128 from L2 (FIRST: FIFO-older) ----
        short8 bh[4], bl[4];
        #pragma unroll
        for (int ks = 0; ks < 4; ++ks) {
            const size_t o = (size_t)(pbase + t * 16 + ks * 4 + fg) * 512 + e8;
            bh[ks] = *(const short8*)(Wp + o);
            bl[ks] = *(const short8*)(Wp + WP_HL + o);
        }
        asm volatile("" ::: "memory");         // pin: W loads precede X DMAs

        // ---- issue next stage's X (in flight across this stage) ----
        if (t + 1 < NSTG) XISSUE(t + 1, (t + 1) & 1)

        // ---- compute stage t ----
        const float* cx = sX[t & 1];
        #pragma unroll
        for (int ks = 0; ks < 4; ++ks) {
            #pragma unroll
            for (int mg = 0; mg < 2; ++mg) {
                const int p0 = (ks * 8 + fg * 2) ^ key;
                const int p1 = (ks * 8 + fg * 2 + 1) ^ key;
                const float4 qa = *(const float4*)&cx[rowA[mg] + (p0 << 2)];
                const float4 qb = *(const float4*)&cx[rowA[mg] + (p1 << 2)];

                // RTZ split fp32 -> bf16 hi/lo (v_perm packing)
                const unsigned int u0 = __float_as_uint(qa.x), u1 = __float_as_uint(qa.y);
                const unsigned int u2 = __float_as_uint(qa.z), u3 = __float_as_uint(qa.w);
                const unsigned int u4 = __float_as_uint(qb.x), u5 = __float_as_uint(qb.y);
                const unsigned int u6 = __float_as_uint(qb.z), u7 = __float_as_uint(qb.w);
                union { unsigned int u[4]; short8 s8; } ah, al;
                ah.u[0] = pack_hi(u0, u1);
                ah.u[1] = pack_hi(u2, u3);
                ah.u[2] = pack_hi(u4, u5);
                ah.u[3] = pack_hi(u6, u7);
                const float l0 = qa.x - __uint_as_float(u0 & 0xFFFF0000u);
                const float l1 = qa.y - __uint_as_float(u1 & 0xFFFF0000u);
                const float l2 = qa.z - __uint_as_float(u2 & 0xFFFF0000u);
                const float l3 = qa.w - __uint_as_float(u3 & 0xFFFF0000u);
                const float l4 = qb.x - __uint_as_float(u4 & 0xFFFF0000u);
                const float l5 = qb.y - __uint_as_float(u5 & 0xFFFF0000u);
                const float l6 = qb.z - __uint_as_float(u6 & 0xFFFF0000u);
                const float l7 = qb.w - __uint_as_float(u7 & 0xFFFF0000u);
                al.u[0] = pack_hi(__float_as_uint(l0), __float_as_uint(l1));
                al.u[1] = pack_hi(__float_as_uint(l2), __float_as_uint(l3));
                al.u[2] = pack_hi(__float_as_uint(l4), __float_as_uint(l5));
                al.u[3] = pack_hi(__float_as_uint(l6), __float_as_uint(l7));

                acc[mg] = __builtin_amdgcn_mfma_f32_16x16x32_bf16(ah.s8, bh[ks], acc[mg], 0, 0, 0);
                acc[mg] = __builtin_amdgcn_mfma_f32_16x16x32_bf16(ah.s8, bl[ks], acc[mg], 0, 0, 0);
                acc[mg] = __builtin_amdgcn_mfma_f32_16x16x32_bf16(al.s8, bh[ks], acc[mg], 0, 0, 0);
            }
        }

        __syncthreads();   // next buffer published (drain covered by co-block)
    }
#undef XISSUE

    // ---- store partials [n][s][e] ----
    // C/D layout: col = fr (expert), row = fg*4 + r (token)
    #pragma unroll
    for (int mg = 0; mg < 2; ++mg)
        #pragma unroll
        for (int r = 0; r < 4; ++r) {
            const int n = tok0 + qm * 32 + mg * 16 + fg * 4 + r;
            part[((size_t)n * SPLITK + s) * NEXP + qn * 16 + fr] = acc[mg][r];
        }
}

// ---------------- Kernel 3: softmax + group-limited top-k routing ------------
__global__ __launch_bounds__(256) void route_kernel(
    const float* __restrict__ part, float* __restrict__ outW,
    float* __restrict__ outI, float* __restrict__ counts)
{
    __shared__ int hist[NEXP];
    const int tid = threadIdx.x;
    if (tid < NEXP) hist[tid] = 0;
    __syncthreads();

    const int lane = tid & 63;
    const int wv   = tid >> 6;   // wave 0..3
    const int tok_base = blockIdx.x * 32 + wv * 8;

    for (int t = 0; t < 8; ++t) {
        const int n = tok_base + t;
        // sum split-K partials (layout [n][s][e]): 1 KB contiguous per token
        float L = 0.0f;
        #pragma unroll
        for (int s = 0; s < SPLITK; ++s)
            L += part[((size_t)n * SPLITK + s) * NEXP + lane];

        // softmax over 64 experts (wave = expert axis)
        float m = L;
        #pragma unroll
        for (int off = 32; off > 0; off >>= 1) m = fmaxf(m, __shfl_xor(m, off));
        float p = expf(L - m);
        float ssum = p;
        #pragma unroll
        for (int off = 32; off > 0; off >>= 1) ssum += __shfl_xor(ssum, off);
        const float score = p / ssum;

        // group max within each 8-lane group
        float gm = score;
        gm = fmaxf(gm, __shfl_xor(gm, 1));
        gm = fmaxf(gm, __shfl_xor(gm, 2));
        gm = fmaxf(gm, __shfl_xor(gm, 4));

        // top-4 groups (ties -> lower index)
        float ga[8];
        #pragma unroll
        for (int g = 0; g < 8; ++g) ga[g] = __shfl(gm, g * 8);
        unsigned selmask = 0u;
        #pragma unroll
        for (int r = 0; r < 4; ++r) {
            float best = -INFINITY; int bg = 0;
            #pragma unroll
            for (int g = 0; g < 8; ++g) {
                bool taken  = (selmask >> g) & 1u;
                bool better = (!taken) && (ga[g] > best);
                bg   = better ? g : bg;
                best = better ? ga[g] : best;
            }
            selmask |= (1u << bg);
        }

        // mask non-selected groups, wave-wide top-4 (ties -> lower idx)
        float ms = ((selmask >> (lane >> 3)) & 1u) ? score : -INFINITY;
        float wk[4]; int wi[4];
        #pragma unroll
        for (int r = 0; r < 4; ++r) {
            float v = ms; int ix = lane;
            #pragma unroll
            for (int off = 32; off > 0; off >>= 1) {
                float vo = __shfl_xor(v, off);
                int   io = __shfl_xor(ix, off);
                if (vo > v || (vo == v && io < ix)) { v = vo; ix = io; }
            }
            wk[r] = v; wi[r] = ix;
            if (lane == ix) ms = -INFINITY;
        }

        if (lane == 0) {
            *(float4*)&outW[(size_t)n * 4] = make_float4(wk[0], wk[1], wk[2], wk[3]);
            *(float4*)&outI[(size_t)n * 4] =
                make_float4((float)wi[0], (float)wi[1], (float)wi[2], (float)wi[3]);
            atomicAdd(&hist[wi[0]], 1);
            atomicAdd(&hist[wi[1]], 1);
            atomicAdd(&hist[wi[2]], 1);
            atomicAdd(&hist[wi[3]], 1);
        }
    }

    __syncthreads();
    if (tid < NEXP) atomicAdd(&counts[tid], (float)hist[tid]);
}

extern "C" void kernel_launch(void* const* d_in, const int* in_sizes, int n_in,
                              void* d_out, int out_size, void* d_ws, size_t ws_size,
                              hipStream_t stream) {
    const float* X = (const float*)d_in[0];
    const float* W = (const float*)d_in[1];

    float* outW   = (float*)d_out;                    // [N,4] weights
    float* outI   = outW + (size_t)NTOK * KTOP;       // [N,4] indices (as float)
    float* counts = outW + (size_t)2 * NTOK * KTOP;   // [64]  counts  (as float)

    float*          part = (float*)d_ws;                              // 16 MB
    unsigned short* Wp   = (unsigned short*)(part + (size_t)NTOK * SPLITK * NEXP);

    prep_kernel<<<(NEXP * DDIM) / 256, 256, 0, stream>>>(W, Wp, counts);
    gemm_kernel<<<NBLK, 512, 0, stream>>>(X, Wp, part);
    route_kernel<<<NTOK / 32, 256, 0, stream>>>(part, outW, outI, counts);
}

// Round 17
// 104.668 us; speedup vs baseline: 5.5218x; 1.0996x over previous
//
#include <hip/hip_runtime.h>
#include <math.h>

// Problem constants
#define NTOK 16384
#define DDIM 4096
#define NEXP 64
#define KTOP 4

// GEMM config
#define SPLITK 8
#define KPER (DDIM / SPLITK)   // 512 k per split
#define BK 32                  // k per ring slot-fill
#define NSTG (KPER / BK)       // 16 slot-fills per block
#define TPB 256                // tokens per block
#define NBLK ((NTOK / TPB) * SPLITK)  // 512 blocks -> 1/CU, 2 rounds
#define NCONS 8                // consumer waves
#define NPROD 4                // producer waves
#define WP_HL 262144           // shorts: Wp hi/lo plane stride (512*64*8)

typedef __attribute__((ext_vector_type(8))) short short8;
typedef __attribute__((ext_vector_type(4))) float f32x4;

// ws layout: part [NTOK][SPLITK][NEXP] f32 = 32 MB ; Wp [2][512][64][8] ushort = 1 MB

__device__ __forceinline__ unsigned short f2bf_rtn(float x) {
    unsigned int b = __float_as_uint(x);
    return (unsigned short)((b + 0x7FFFu + ((b >> 16) & 1u)) >> 16);
}
__device__ __forceinline__ float bf2f(unsigned short h) {
    return __uint_as_float(((unsigned int)h) << 16);
}
__device__ __forceinline__ void gl2lds16(const void* g, void* l) {
    __builtin_amdgcn_global_load_lds(
        (const __attribute__((address_space(1))) unsigned int*)g,
        (__attribute__((address_space(3))) unsigned int*)l, 16, 0, 0);
}
__device__ __forceinline__ unsigned int pack_hi(unsigned int u0, unsigned int u1) {
    return __builtin_amdgcn_perm(u1, u0, 0x07060302u);
}
__device__ __forceinline__ void poll_ge(unsigned* p, unsigned tgt) {
    while (__hip_atomic_load(p, __ATOMIC_ACQUIRE, __HIP_MEMORY_SCOPE_WORKGROUP) < tgt)
        __builtin_amdgcn_s_sleep(1);
    __builtin_amdgcn_sched_barrier(0);
}

// ---------------- Kernel 1: W -> piece-major bf16 hi/lo, zero counts ---------
__global__ __launch_bounds__(256) void prep_kernel(
    const float* __restrict__ W, unsigned short* __restrict__ Wp,
    float* __restrict__ counts)
{
    int idx = blockIdx.x * 256 + threadIdx.x;   // e*4096 + d
    int e = idx >> 12, d = idx & 4095;
    float x = W[idx];
    unsigned short h = f2bf_rtn(x);
    float lo = x - bf2f(h);
    size_t o = (((size_t)(d >> 3)) * 64 + e) * 8 + (d & 7);
    Wp[o]         = h;
    Wp[WP_HL + o] = f2bf_rtn(lo);
    if (blockIdx.x == 0 && threadIdx.x < NEXP) counts[threadIdx.x] = 0.0f;
}

// ---------------- Kernel 2: producer/consumer wave-specialized GEMM ----------
// 512 blocks x 768 threads (12 waves), LDS 128 KB ring -> 1 block/CU, 2 rounds.
// 4 PRODUCER waves stream X through a 4-slot ring (8 x 1-KB DMA/slot each,
// counted vmcnt(8), no barriers) -- the memory pipe never pauses for compute.
// 8 CONSUMER waves (2qm x 4qn, 128 tok x 16 exp) poll per-slot LDS flags,
// compute 24 MFMAs/slot each, and release the slot. W: piece-major L2 regs.
__global__ __launch_bounds__(768, 3) void gemm_kernel(
    const float* __restrict__ X, const unsigned short* __restrict__ Wp,
    float* __restrict__ part)
{
    __shared__ float ring[4][TPB * BK];   // 4 x 32 KB
    __shared__ unsigned rdy[4];           // producer fills (4 per slot-fill)
    __shared__ unsigned dn[4];            // consumer releases (8 per slot-fill)

    const int tid  = threadIdx.x;
    const int lane = tid & 63;
    const int w    = tid >> 6;                 // wave 0..11
    const int tb   = blockIdx.x >> 3;          // token block 0..63
    const int s    = blockIdx.x & 7;           // k-split    0..7
    const int kbase = s * KPER;
    const int tok0 = tb * TPB;

    if (tid < 4) rdy[tid] = 0;
    else if (tid < 8) dn[tid - 4] = 0;
    __syncthreads();   // the ONLY block barrier (flags published)

    if (w >= NCONS) {
        // ================= PRODUCER (waves 8..11) =================
        const int pw = w - NCONS;              // 0..3, covers rows pw*64..+63
        const float* src[8];
        int dst[8];
        #pragma unroll
        for (int j = 0; j < 8; ++j) {
            const int r = pw * 64 + j * 8 + (lane >> 3);
            src[j] = X + (size_t)(tok0 + r) * DDIM + kbase
                   + (((lane & 7) ^ (r & 7)) << 2);       // src-side XOR swizzle
            dst[j] = (pw * 64 + j * 8) * BK;              // wave-uniform base
        }
        #pragma unroll 1
        for (int st = 0; st < NSTG; ++st) {
            const int slot = st & 3;
            if (st >= 4) poll_ge(&dn[slot], 8u * (unsigned)(st >> 2));
            #pragma unroll
            for (int j = 0; j < 8; ++j)
                gl2lds16(src[j] + st * BK, &ring[slot][dst[j]]);
            if (st >= 1) {
                asm volatile("s_waitcnt vmcnt(8)" ::: "memory");  // slot st-1 done
                if (lane == 0)
                    __hip_atomic_fetch_add(&rdy[(st - 1) & 3], 1u,
                        __ATOMIC_RELEASE, __HIP_MEMORY_SCOPE_WORKGROUP);
            }
        }
        asm volatile("s_waitcnt vmcnt(0)" ::: "memory");
        if (lane == 0)
            __hip_atomic_fetch_add(&rdy[(NSTG - 1) & 3], 1u,
                __ATOMIC_RELEASE, __HIP_MEMORY_SCOPE_WORKGROUP);
        return;                                // producers exit
    }

    // ================= CONSUMER (waves 0..7) =================
    const int qm = w >> 2;                     // token half 0..1 (128 rows)
    const int qn = w & 3;                      // expert quarter 0..3
    const int fr = lane & 15;                  // token row / expert col in frag
    const int fg = lane >> 4;                  // k subgroup 0..3
    const int key = fr & 7;
    const int e8  = (qn * 16 + fr) * 8;        // Wp expert offset (shorts)
    const int pb  = kbase >> 3;                // global 8-float piece base

    f32x4 acc[8];
    #pragma unroll
    for (int mg = 0; mg < 8; ++mg) acc[mg] = (f32x4){0.f, 0.f, 0.f, 0.f};

    // W double-buffer (static parity under full unroll)
    short8 bh0, bl0, bh1, bl1;
    {
        const size_t o = (size_t)(pb + 0 * 4 + fg) * 512 + e8;
        bh0 = *(const short8*)(Wp + o);
        bl0 = *(const short8*)(Wp + WP_HL + o);
    }

    #pragma unroll
    for (int st = 0; st < NSTG; ++st) {
        const int slot = st & 3;
        // wait: all 4 producers marked this fill
        poll_ge(&rdy[slot], 4u * (unsigned)((st >> 2) + 1));

        // prefetch next stage's W (L2, hides under compute)
        if (st + 1 < NSTG) {
            const size_t o = (size_t)(pb + (st + 1) * 4 + fg) * 512 + e8;
            if ((st & 1) == 0) { bh1 = *(const short8*)(Wp + o);
                                 bl1 = *(const short8*)(Wp + WP_HL + o); }
            else               { bh0 = *(const short8*)(Wp + o);
                                 bl0 = *(const short8*)(Wp + WP_HL + o); }
        }
        const short8 bh = (st & 1) ? bh1 : bh0;
        const short8 bl = (st & 1) ? bl1 : bl0;

        const float* cx = ring[slot];
        #pragma unroll
        for (int mg = 0; mg < 8; ++mg) {
            const int lr = qm * 128 + mg * 16 + fr;
            const int p0 = (fg * 2) ^ key;
            const float4 qa = *(const float4*)&cx[lr * BK + (p0 << 2)];
            const float4 qb = *(const float4*)&cx[lr * BK + ((p0 ^ 1) << 2)];

            // RTZ split fp32 -> bf16 hi/lo (v_perm packing)
            const unsigned int u0 = __float_as_uint(qa.x), u1 = __float_as_uint(qa.y);
            const unsigned int u2 = __float_as_uint(qa.z), u3 = __float_as_uint(qa.w);
            const unsigned int u4 = __float_as_uint(qb.x), u5 = __float_as_uint(qb.y);
            const unsigned int u6 = __float_as_uint(qb.z), u7 = __float_as_uint(qb.w);
            union { unsigned int u[4]; short8 s8; } ah, al;
            ah.u[0] = pack_hi(u0, u1);
            ah.u[1] = pack_hi(u2, u3);
            ah.u[2] = pack_hi(u4, u5);
            ah.u[3] = pack_hi(u6, u7);
            const float l0 = qa.x - __uint_as_float(u0 & 0xFFFF0000u);
            const float l1 = qa.y - __uint_as_float(u1 & 0xFFFF0000u);
            const float l2 = qa.z - __uint_as_float(u2 & 0xFFFF0000u);
            const float l3 = qa.w - __uint_as_float(u3 & 0xFFFF0000u);
            const float l4 = qb.x - __uint_as_float(u4 & 0xFFFF0000u);
            const float l5 = qb.y - __uint_as_float(u5 & 0xFFFF0000u);
            const float l6 = qb.z - __uint_as_float(u6 & 0xFFFF0000u);
            const float l7 = qb.w - __uint_as_float(u7 & 0xFFFF0000u);
            al.u[0] = pack_hi(__float_as_uint(l0), __float_as_uint(l1));
            al.u[1] = pack_hi(__float_as_uint(l2), __float_as_uint(l3));
            al.u[2] = pack_hi(__float_as_uint(l4), __float_as_uint(l5));
            al.u[3] = pack_hi(__float_as_uint(l6), __float_as_uint(l7));

            acc[mg] = __builtin_amdgcn_mfma_f32_16x16x32_bf16(ah.s8, bh, acc[mg], 0, 0, 0);
            acc[mg] = __builtin_amdgcn_mfma_f32_16x16x32_bf16(ah.s8, bl, acc[mg], 0, 0, 0);
            acc[mg] = __builtin_amdgcn_mfma_f32_16x16x32_bf16(al.s8, bh, acc[mg], 0, 0, 0);
        }

        // release the slot (orders the ds_reads above)
        if (lane == 0)
            __hip_atomic_fetch_add(&dn[slot], 1u,
                __ATOMIC_RELEASE, __HIP_MEMORY_SCOPE_WORKGROUP);
    }

    // ---- store partials [n][s][e] ----
    // C/D layout: col = fr (expert), row = fg*4 + r (token)
    #pragma unroll
    for (int mg = 0; mg < 8; ++mg)
        #pragma unroll
        for (int r = 0; r < 4; ++r) {
            const int n = tok0 + qm * 128 + mg * 16 + fg * 4 + r;
            part[((size_t)n * SPLITK + s) * NEXP + qn * 16 + fr] = acc[mg][r];
        }
}

// ---------------- Kernel 3: softmax + group-limited top-k routing ------------
__global__ __launch_bounds__(256) void route_kernel(
    const float* __restrict__ part, float* __restrict__ outW,
    float* __restrict__ outI, float* __restrict__ counts)
{
    __shared__ int hist[NEXP];
    const int tid = threadIdx.x;
    if (tid < NEXP) hist[tid] = 0;
    __syncthreads();

    const int lane = tid & 63;
    const int wv   = tid >> 6;   // wave 0..3
    const int tok_base = blockIdx.x * 32 + wv * 8;

    for (int t = 0; t < 8; ++t) {
        const int n = tok_base + t;
        // sum split-K partials (layout [n][s][e]): 2 KB contiguous per token
        float L = 0.0f;
        #pragma unroll
        for (int s = 0; s < SPLITK; ++s)
            L += part[((size_t)n * SPLITK + s) * NEXP + lane];

        // softmax over 64 experts (wave = expert axis)
        float m = L;
        #pragma unroll
        for (int off = 32; off > 0; off >>= 1) m = fmaxf(m, __shfl_xor(m, off));
        float p = expf(L - m);
        float ssum = p;
        #pragma unroll
        for (int off = 32; off > 0; off >>= 1) ssum += __shfl_xor(ssum, off);
        const float score = p / ssum;

        // group max within each 8-lane group
        float gm = score;
        gm = fmaxf(gm, __shfl_xor(gm, 1));
        gm = fmaxf(gm, __shfl_xor(gm, 2));
        gm = fmaxf(gm, __shfl_xor(gm, 4));

        // top-4 groups (ties -> lower index)
        float ga[8];
        #pragma unroll
        for (int g = 0; g < 8; ++g) ga[g] = __shfl(gm, g * 8);
        unsigned selmask = 0u;
        #pragma unroll
        for (int r = 0; r < 4; ++r) {
            float best = -INFINITY; int bg = 0;
            #pragma unroll
            for (int g = 0; g < 8; ++g) {
                bool taken  = (selmask >> g) & 1u;
                bool better = (!taken) && (ga[g] > best);
                bg   = better ? g : bg;
                best = better ? ga[g] : best;
            }
            selmask |= (1u << bg);
        }

        // mask non-selected groups, wave-wide top-4 (ties -> lower idx)
        float ms = ((selmask >> (lane >> 3)) & 1u) ? score : -INFINITY;
        float wk[4]; int wi[4];
        #pragma unroll
        for (int r = 0; r < 4; ++r) {
            float v = ms; int ix = lane;
            #pragma unroll
            for (int off = 32; off > 0; off >>= 1) {
                float vo = __shfl_xor(v, off);
                int   io = __shfl_xor(ix, off);
                if (vo > v || (vo == v && io < ix)) { v = vo; ix = io; }
            }
            wk[r] = v; wi[r] = ix;
            if (lane == ix) ms = -INFINITY;
        }

        if (lane == 0) {
            *(float4*)&outW[(size_t)n * 4] = make_float4(wk[0], wk[1], wk[2], wk[3]);
            *(float4*)&outI[(size_t)n * 4] =
                make_float4((float)wi[0], (float)wi[1], (float)wi[2], (float)wi[3]);
            atomicAdd(&hist[wi[0]], 1);
            atomicAdd(&hist[wi[1]], 1);
            atomicAdd(&hist[wi[2]], 1);
            atomicAdd(&hist[wi[3]], 1);
        }
    }

    __syncthreads();
    if (tid < NEXP) atomicAdd(&counts[tid], (float)hist[tid]);
}

extern "C" void kernel_launch(void* const* d_in, const int* in_sizes, int n_in,
                              void* d_out, int out_size, void* d_ws, size_t ws_size,
                              hipStream_t stream) {
    const float* X = (const float*)d_in[0];
    const float* W = (const float*)d_in[1];

    float* outW   = (float*)d_out;                    // [N,4] weights
    float* outI   = outW + (size_t)NTOK * KTOP;       // [N,4] indices (as float)
    float* counts = outW + (size_t)2 * NTOK * KTOP;   // [64]  counts  (as float)

    float*          part = (float*)d_ws;                              // 32 MB
    unsigned short* Wp   = (unsigned short*)(part + (size_t)NTOK * SPLITK * NEXP);

    prep_kernel<<<(NEXP * DDIM) / 256, 256, 0, stream>>>(W, Wp, counts);
    gemm_kernel<<<NBLK, (NCONS + NPROD) * 64, 0, stream>>>(X, Wp, part);
    route_kernel<<<NTOK / 32, 256, 0, stream>>>(part, outW, outI, counts);
}